// Round 10
// baseline (174.670 us; speedup 1.0000x reference)
//
#include <hip/hip_runtime.h>
#include <math.h>

// ---------------- workspace layout (float offsets) ----------------
// W2P folded (v1+v4 -> one column): [64][192], row-major [c][o] so lane o is coalesced.
#define OFF_W2P 0              // [64][192]
#define OFF_B2P 12288          // [192]
#define WS_FLOATS 12480

#define SC_Y0 0.0180421959121758f   // (1/sqrt(32))*(1/sqrt(96))
#define SC_Y2 0.015625f             // (1/sqrt(32))*(1/sqrt(128))
#define S2f 0.70710678118654752f
#define S6f 0.40824829046386302f
#define TWOS2f 1.41421356237309505f
#define TWOS6f 0.81649658092772603f
#define ISQRT3 0.57735026918962576f
#define ISQRT5 0.44721359549995794f
#define H0SC 0.08838834764831845f   // 1/sqrt(128)
#define H1SC 0.125f                 // 1/sqrt(64)
#define H2SC 0.17677669529663689f   // 1/sqrt(32)

#define COMP(v, q) ((q) == 0 ? (v).x : (q) == 1 ? (v).y : (q) == 2 ? (v).z : (v).w)

__device__ static inline float dot32(const float* __restrict__ a,
                                     const float* __restrict__ b) {
  const float4* a4 = (const float4*)a;
  const float4* b4 = (const float4*)b;
  float acc = 0.f;
#pragma unroll
  for (int q = 0; q < 8; ++q) {
    float4 x = a4[q], y = b4[q];
    acc += x.x * y.x + x.y * y.y + x.z * y.z + x.w * y.w;
  }
  return acc;
}

// ---------------- prep: folded W2P[c][o], B2P, zero out ----------------
__global__ __launch_bounds__(256) void prep_kernel(
    const float* __restrict__ Wm2, const float* __restrict__ bm2,
    const float* __restrict__ P0, const float* __restrict__ P2,
    float* __restrict__ ws, float* __restrict__ out) {
  int j = blockIdx.x * 256 + threadIdx.x;
  if (j < 2304) out[j] = 0.f;

  if (j < 12288) {
    const int c = j / 192, o = j % 192;
    const int s = o >> 5, u = o & 31;
    int k; const float* P; float sc;
    switch (s) {
      case 0: k = 0; P = P0;      sc = SC_Y0; break;
      case 1: k = 1; P = P2;      sc = SC_Y2; break;
      case 2: k = 2; P = P0 + 32; sc = SC_Y0; break;
      case 3: k = 4; P = P2 + 32; sc = SC_Y2; break;
      case 4: k = 6; P = P0 + 64; sc = SC_Y0; break;
      default: k = 8; P = P2 + 96; sc = SC_Y2; break;
    }
    float acc = dot32(Wm2 + c * 9216 + k * 1024 + u * 32, P);
    if (s == 1) acc += dot32(Wm2 + c * 9216 + 5 * 1024 + u * 32, P2 + 64);
    ws[OFF_W2P + j] = acc * sc;
  } else if (j < 12480) {
    const int o = j - 12288;
    const int s = o >> 5, u = o & 31;
    int k; const float* P; float sc;
    switch (s) {
      case 0: k = 0; P = P0;      sc = SC_Y0; break;
      case 1: k = 1; P = P2;      sc = SC_Y2; break;
      case 2: k = 2; P = P0 + 32; sc = SC_Y0; break;
      case 3: k = 4; P = P2 + 32; sc = SC_Y2; break;
      case 4: k = 6; P = P0 + 64; sc = SC_Y0; break;
      default: k = 8; P = P2 + 96; sc = SC_Y2; break;
    }
    float acc = dot32(bm2 + k * 1024 + u * 32, P);
    if (s == 1) acc += dot32(bm2 + 5 * 1024 + u * 32, P2 + 64);
    ws[OFF_B2P + o] = acc * sc;
  }
}

// ---------------- fused: 32-node tile; (1n x 4u) phase B on ALL 256 threads ----------------
// R9 post-mortem: the 5.6 FMA/load mapping works but must run on the full block.
// 32-node tile makes (n in 32) x (ug in 8) = 256 threads.
//   phase 2: 2n x 4c            -> 1024 FMA / 192 loads = 5.3 FMA/load
//   phase B: 1n x 4u            -> 1920 FMA / 344 loads = 5.6 FMA/load (full block)
//   phase 3: acc[32]/thread     -> 64 w-loads for 32 nodes
// LDS 70912 B -> 2 blocks/CU: xp[32][484] (484%32=4: 8 rows/wave spread all 32 banks,
// conflict-free b128 reads) + hi2[32][64] + sphs[32][6]; Vt[32][193] overlays dead xp
// (193%32=1 -> phase-D scalar reads <=2-way aliasing = free, m136).
// (256,4): 128-VGPR cap; peak live ~100 (36 carried h-accs + phase-3 ~48) - margin kept.
__global__ __launch_bounds__(256, 4) void fused_kernel(
    const float* __restrict__ xs_g, const float* __restrict__ xsph,
    const float* __restrict__ W0e, const float* __restrict__ W1o,
    const float* __restrict__ W2e,
    const float* __restrict__ Wm1, const float* __restrict__ bm1,
    const float* __restrict__ ws, const int* __restrict__ batch,
    float* __restrict__ out, const float norm2) {
  __shared__ __align__(16) float smem[17728];
  float (*xp)[484] = (float (*)[484])smem;                 // [0, 15488)
  float (*Vt)[193] = (float (*)[193])smem;                 // overlays xp after phase B
  float (*hi2)[64] = (float (*)[64])(smem + 15488);        // [15488, 17536)
  float (*sphs)[6] = (float (*)[6])(smem + 17536);         // [17536, 17728)

  const int tid = threadIdx.x;
  const int n0 = blockIdx.x * 32;

  // ---- stage-issue: x_sph (32x480 = 3840 float4) into registers (T14 split) ----
  float4 st[15];
#pragma unroll
  for (int k = 0; k < 15; ++k) {
    const int d = tid + k * 256;
    const int r = d / 120, c = d % 120;
    st[k] = *(const float4*)(xsph + (size_t)(n0 + r) * 480 + c * 4);
  }

  // ---- phase 2 (hides staging latency): hidden = silu(x_scalar @ Wm1 + bm1) ----
  // thread = (2 nodes nb,nb+1; 4 channels c0..c0+3): w float4 feeds 2 nodes.
  {
    const int nb = (tid >> 4) * 2, c0 = (tid & 15) * 4;
    const float* xrA = xs_g + (size_t)(n0 + nb) * 128;
    const float* xrB = xrA + 128;
    float accA[4] = {0.f, 0.f, 0.f, 0.f};
    float accB[4] = {0.f, 0.f, 0.f, 0.f};
#pragma unroll 4
    for (int mq = 0; mq < 32; ++mq) {
      const float4 xa = *(const float4*)(xrA + mq * 4);
      const float4 xb = *(const float4*)(xrB + mq * 4);
#pragma unroll
      for (int r = 0; r < 4; ++r) {
        const float4 w = *(const float4*)(Wm1 + (mq * 4 + r) * 64 + c0);
        const float fa = COMP(xa, r), fb = COMP(xb, r);
        accA[0] += fa * w.x; accA[1] += fa * w.y; accA[2] += fa * w.z; accA[3] += fa * w.w;
        accB[0] += fb * w.x; accB[1] += fb * w.y; accB[2] += fb * w.z; accB[3] += fb * w.w;
      }
    }
    const float4 bb = *(const float4*)(bm1 + c0);
    const float ba[4] = {bb.x, bb.y, bb.z, bb.w};
    float4 sA, sB;
    {
      const float z0 = accA[0] + ba[0], z1 = accA[1] + ba[1];
      const float z2 = accA[2] + ba[2], z3 = accA[3] + ba[3];
      sA.x = z0 / (1.f + __expf(-z0)); sA.y = z1 / (1.f + __expf(-z1));
      sA.z = z2 / (1.f + __expf(-z2)); sA.w = z3 / (1.f + __expf(-z3));
    }
    {
      const float z0 = accB[0] + ba[0], z1 = accB[1] + ba[1];
      const float z2 = accB[2] + ba[2], z3 = accB[3] + ba[3];
      sB.x = z0 / (1.f + __expf(-z0)); sB.y = z1 / (1.f + __expf(-z1));
      sB.z = z2 / (1.f + __expf(-z2)); sB.w = z3 / (1.f + __expf(-z3));
    }
    *(float4*)&hi2[nb][c0] = sA;
    *(float4*)&hi2[nb + 1][c0] = sB;
  }

  // ---- stage-write: commit x_sph registers to LDS ----
#pragma unroll
  for (int k = 0; k < 15; ++k) {
    const int d = tid + k * 256;
    const int r = d / 120, c = d % 120;
    *(float4*)&xp[r][c * 4] = st[k];
  }
  __syncthreads();  // xp + hi2 ready

  // ---- phase B: h0/h1/h2; thread = (n = tid>>3, ug = tid&7 -> u0 = ug*4) ----
  const int n = tid >> 3, ug = tid & 7, u0 = ug * 4;
  const float* row = xp[n];
  float4 acc0 = {0.f, 0.f, 0.f, 0.f};
  float4 acc1[3];
  float4 acc2[5];

  // h0: K=128, 4 u via float4 weight rows
#pragma unroll 4
  for (int mq = 0; mq < 32; ++mq) {
    const float4 xv = *(const float4*)(row + mq * 4);
#pragma unroll
    for (int r = 0; r < 4; ++r) {
      const float4 w = *(const float4*)(W0e + (mq * 4 + r) * 32 + u0);
      const float xr = COMP(xv, r);
      acc0.x += xr * w.x; acc0.y += xr * w.y;
      acc0.z += xr * w.z; acc0.w += xr * w.w;
    }
  }
  // h1: K=64, 3 comps
#pragma unroll
  for (int j = 0; j < 3; ++j) acc1[j] = make_float4(0.f, 0.f, 0.f, 0.f);
#pragma unroll 2
  for (int mq = 0; mq < 16; ++mq) {
    const float4 b0 = *(const float4*)(row + 128 + mq * 12);
    const float4 b1 = *(const float4*)(row + 128 + mq * 12 + 4);
    const float4 b2 = *(const float4*)(row + 128 + mq * 12 + 8);
    const float xa[12] = {b0.x, b0.y, b0.z, b0.w, b1.x, b1.y, b1.z, b1.w,
                          b2.x, b2.y, b2.z, b2.w};
#pragma unroll
    for (int mm = 0; mm < 4; ++mm) {
      const float4 w = *(const float4*)(W1o + (mq * 4 + mm) * 32 + u0);
#pragma unroll
      for (int j = 0; j < 3; ++j) {
        const float xr = xa[mm * 3 + j];
        acc1[j].x += xr * w.x; acc1[j].y += xr * w.y;
        acc1[j].z += xr * w.z; acc1[j].w += xr * w.w;
      }
    }
  }
  // h2: K=32, 5 comps
#pragma unroll
  for (int j = 0; j < 5; ++j) acc2[j] = make_float4(0.f, 0.f, 0.f, 0.f);
#pragma unroll 2
  for (int mq = 0; mq < 8; ++mq) {
    const float4 c0v = *(const float4*)(row + 320 + mq * 20);
    const float4 c1v = *(const float4*)(row + 320 + mq * 20 + 4);
    const float4 c2v = *(const float4*)(row + 320 + mq * 20 + 8);
    const float4 c3v = *(const float4*)(row + 320 + mq * 20 + 12);
    const float4 c4v = *(const float4*)(row + 320 + mq * 20 + 16);
    const float xa[20] = {c0v.x, c0v.y, c0v.z, c0v.w, c1v.x, c1v.y, c1v.z, c1v.w,
                          c2v.x, c2v.y, c2v.z, c2v.w, c3v.x, c3v.y, c3v.z, c3v.w,
                          c4v.x, c4v.y, c4v.z, c4v.w};
#pragma unroll
    for (int mm = 0; mm < 4; ++mm) {
      const float4 w = *(const float4*)(W2e + (mq * 4 + mm) * 32 + u0);
#pragma unroll
      for (int j = 0; j < 5; ++j) {
        const float xr = xa[mm * 5 + j];
        acc2[j].x += xr * w.x; acc2[j].y += xr * w.y;
        acc2[j].z += xr * w.z; acc2[j].w += xr * w.w;
      }
    }
  }
  __syncthreads();  // xp fully consumed -> Vt may overlay

  // ---- phase 3: V[n][o] = b2p[o] + sum_c hi2[n][c]*W2P[c][o]; 32 nodes/thread ----
  if (tid < 192) {
    const int o = tid;
    float acc[32];
    {
      const float b = ws[OFF_B2P + o];
#pragma unroll
      for (int nn = 0; nn < 32; ++nn) acc[nn] = b;
    }
    for (int c4 = 0; c4 < 64; c4 += 4) {
      const float w0 = ws[OFF_W2P + (c4 + 0) * 192 + o];  // coalesced; feeds 32 FMAs
      const float w1 = ws[OFF_W2P + (c4 + 1) * 192 + o];
      const float w2 = ws[OFF_W2P + (c4 + 2) * 192 + o];
      const float w3 = ws[OFF_W2P + (c4 + 3) * 192 + o];
#pragma unroll
      for (int nn = 0; nn < 32; ++nn) {
        const float4 h = *(const float4*)&hi2[nn][c4];    // broadcast
        acc[nn] += h.x * w0 + h.y * w1 + h.z * w2 + h.w * w3;
      }
    }
#pragma unroll
    for (int nn = 0; nn < 32; ++nn) Vt[nn][o] = acc[nn];
  }
  __syncthreads();  // Vt ready; h accs live in registers

  // ---- phase D: path math for 4 u's + in-thread sum + 8-lane shfl reduce ----
  {
    float y0s = 0.f;
    float y2s[5] = {0.f, 0.f, 0.f, 0.f, 0.f};
#pragma unroll
    for (int q = 0; q < 4; ++q) {
      const int u = u0 + q;
      const float* Vp = &Vt[n][u];
      const float v0 = Vp[0], v15 = Vp[32], v2 = Vp[64], v3 = Vp[96];
      const float v5 = Vp[128], v6 = Vp[160];

      const float h0 = COMP(acc0, q) * H0SC;
      const float h1a = COMP(acc1[0], q) * H1SC;
      const float h1b = COMP(acc1[1], q) * H1SC;
      const float h1c = COMP(acc1[2], q) * H1SC;
      float h2v[5];
#pragma unroll
      for (int jj = 0; jj < 5; ++jj) h2v[jj] = COMP(acc2[jj], q) * H2SC;

      const float d11 = h1a * h1a + h1b * h1b + h1c * h1c;
      const float d22 = h2v[0] * h2v[0] + h2v[1] * h2v[1] + h2v[2] * h2v[2] +
                        h2v[3] * h2v[3] + h2v[4] * h2v[4];
      const float y0 = v0 * h0 * h0 + v2 * d11 * ISQRT3 + v5 * d22 * ISQRT5;

      const float o00 = h1a * h1a, o01 = h1a * h1b, o02 = h1a * h1c;
      const float o11 = h1b * h1b, o12 = h1b * h1c, o22 = h1c * h1c;
      const float t40 = TWOS2f * o01, t41 = TWOS2f * o12;
      const float t42 = S6f * (2.f * o22 - o00 - o11);
      const float t43 = TWOS2f * o02, t44 = S2f * (o00 - o11);

      const float A00 = -S6f * h2v[2] + S2f * h2v[4];
      const float A01 = S2f * h2v[0];
      const float A02 = S2f * h2v[3];
      const float A11 = -S6f * h2v[2] - S2f * h2v[4];
      const float A12 = S2f * h2v[1];
      const float A22 = TWOS6f * h2v[2];
      const float B00 = A00 * A00 + A01 * A01 + A02 * A02;
      const float B01 = A00 * A01 + A01 * A11 + A02 * A12;
      const float B02 = A00 * A02 + A01 * A12 + A02 * A22;
      const float B11 = A01 * A01 + A11 * A11 + A12 * A12;
      const float B12 = A01 * A02 + A11 * A12 + A12 * A22;
      const float B22 = A02 * A02 + A12 * A12 + A22 * A22;
      const float t80 = TWOS2f * B01, t81 = TWOS2f * B12;
      const float t82 = S6f * (2.f * B22 - B00 - B11);
      const float t83 = TWOS2f * B02, t84 = S2f * (B00 - B11);

      const float w15 = v15 * h0;
      const float v6n = v6 * norm2;
      y0s += y0;
      y2s[0] += w15 * h2v[0] + v3 * t40 + v6n * t80;
      y2s[1] += w15 * h2v[1] + v3 * t41 + v6n * t81;
      y2s[2] += w15 * h2v[2] + v3 * t42 + v6n * t82;
      y2s[3] += w15 * h2v[3] + v3 * t43 + v6n * t83;
      y2s[4] += w15 * h2v[4] + v3 * t44 + v6n * t84;
    }

#pragma unroll
    for (int off = 4; off > 0; off >>= 1) {
      y0s += __shfl_xor(y0s, off, 8);
#pragma unroll
      for (int r = 0; r < 5; ++r) y2s[r] += __shfl_xor(y2s[r], off, 8);
    }

    if (ug == 0) {
      sphs[n][0] = y0s;
#pragma unroll
      for (int r = 0; r < 5; ++r) sphs[n][1 + r] = y2s[r];
    }
  }
  __syncthreads();

  // ---- phase E: Q-contract + segment atomics over the 32-node tile ----
  if (tid < 9) {
    const float QW[9][6] = {
        {ISQRT3, 0.f, 0.f, -S6f, 0.f, S2f},
        {0.f, S2f, 0.f, 0.f, 0.f, 0.f},
        {0.f, 0.f, 0.f, 0.f, S2f, 0.f},
        {0.f, S2f, 0.f, 0.f, 0.f, 0.f},
        {ISQRT3, 0.f, 0.f, -S6f, 0.f, -S2f},
        {0.f, 0.f, S2f, 0.f, 0.f, 0.f},
        {0.f, 0.f, 0.f, 0.f, S2f, 0.f},
        {0.f, 0.f, S2f, 0.f, 0.f, 0.f},
        {ISQRT3, 0.f, 0.f, TWOS6f, 0.f, 0.f}};
    const int a = tid / 3, b = tid % 3;
    const int rolled = ((a + 1) % 3) * 3 + ((b + 1) % 3);
    const float c0 = QW[tid][0], c1 = QW[tid][1], c2 = QW[tid][2];
    const float c3 = QW[tid][3], c4 = QW[tid][4], c5 = QW[tid][5];
    int cur_g = batch[n0];
    float acc = 0.f;
#pragma unroll
    for (int q = 0; q < 32; ++q) {
      const int g = batch[n0 + q];
      const float val = c0 * sphs[q][0] + c1 * sphs[q][1] + c2 * sphs[q][2] +
                        c3 * sphs[q][3] + c4 * sphs[q][4] + c5 * sphs[q][5];
      if (g != cur_g) {
        atomicAdd(out + cur_g * 9 + rolled, acc);
        acc = 0.f;
        cur_g = g;
      }
      acc += val;
    }
    atomicAdd(out + cur_g * 9 + rolled, acc);
  }
}

extern "C" void kernel_launch(void* const* d_in, const int* in_sizes, int n_in,
                              void* d_out, int out_size, void* d_ws, size_t ws_size,
                              hipStream_t stream) {
  const float* x_scalar = (const float*)d_in[0];
  const float* x_sph    = (const float*)d_in[1];
  const int*   batch    = (const int*)d_in[2];
  const float* W0e      = (const float*)d_in[3];
  const float* W1o      = (const float*)d_in[4];
  const float* W2e      = (const float*)d_in[5];
  const float* Wm1      = (const float*)d_in[6];
  const float* bm1      = (const float*)d_in[7];
  const float* Wm2      = (const float*)d_in[8];
  const float* bm2      = (const float*)d_in[9];
  const float* P0       = (const float*)d_in[10];
  // P1 (d_in[11]) provably unused: C111/C221 antisymmetric vs h(x)h of same h.
  const float* P2       = (const float*)d_in[12];
  float* ws  = (float*)d_ws;
  float* out = (float*)d_out;

  if (ws_size < (size_t)WS_FLOATS * sizeof(float)) return;

  // host-side C222 normalization (pure CPU double math; = sqrt(12/7))
  double Q2[5][3][3] = {};
  const double s2d = 0.70710678118654752440, s6d = 0.40824829046386301637;
  Q2[0][0][1] = Q2[0][1][0] = s2d;
  Q2[1][1][2] = Q2[1][2][1] = s2d;
  Q2[2][0][0] = Q2[2][1][1] = -s6d; Q2[2][2][2] = 2.0 * s6d;
  Q2[3][0][2] = Q2[3][2][0] = s2d;
  Q2[4][0][0] = s2d; Q2[4][1][1] = -s2d;
  double ss = 0.0;
  for (int i = 0; i < 5; ++i)
    for (int jj = 0; jj < 5; ++jj) {
      double S[3][3];
      for (int a = 0; a < 3; ++a)
        for (int d = 0; d < 3; ++d) {
          double m1 = 0, m2 = 0;
          for (int b = 0; b < 3; ++b) {
            m1 += Q2[i][a][b] * Q2[jj][d][b];
            m2 += Q2[i][d][b] * Q2[jj][a][b];
          }
          S[a][d] = 0.5 * (m1 + m2);
        }
      double tr = (S[0][0] + S[1][1] + S[2][2]) / 3.0;
      S[0][0] -= tr; S[1][1] -= tr; S[2][2] -= tr;
      for (int kk = 0; kk < 5; ++kk) {
        double cc = 0;
        for (int a = 0; a < 3; ++a)
          for (int d = 0; d < 3; ++d) cc += Q2[kk][a][d] * S[a][d];
        ss += cc * cc;
      }
    }
  const float norm2 = (float)sqrt(5.0 / ss);

  prep_kernel<<<49, 256, 0, stream>>>(Wm2, bm2, P0, P2, ws, out);
  fused_kernel<<<625, 256, 0, stream>>>(x_scalar, x_sph, W0e, W1o, W2e,
                                        Wm1, bm1, ws, batch, out, norm2);
}

// Round 11
// 166.557 us; speedup vs baseline: 1.0487x; 1.0487x over previous
//
#include <hip/hip_runtime.h>
#include <math.h>

// ---------------- workspace layout (float offsets) ----------------
// W2P folded (v1+v4 -> one column): [64][192], row-major [c][o] so lane o is coalesced.
#define OFF_W2P 0              // [64][192]
#define OFF_B2P 12288          // [192]
#define WS_FLOATS 12480

#define SC_Y0 0.0180421959121758f   // (1/sqrt(32))*(1/sqrt(96))
#define SC_Y2 0.015625f             // (1/sqrt(32))*(1/sqrt(128))
#define S2f 0.70710678118654752f
#define S6f 0.40824829046386302f
#define TWOS2f 1.41421356237309505f
#define TWOS6f 0.81649658092772603f
#define ISQRT3 0.57735026918962576f
#define ISQRT5 0.44721359549995794f
#define H0SC 0.08838834764831845f   // 1/sqrt(128)
#define H1SC 0.125f                 // 1/sqrt(64)
#define H2SC 0.17677669529663689f   // 1/sqrt(32)

#define COMP(v, q) ((q) == 0 ? (v).x : (q) == 1 ? (v).y : (q) == 2 ? (v).z : (v).w)

__device__ static inline float dot32(const float* __restrict__ a,
                                     const float* __restrict__ b) {
  const float4* a4 = (const float4*)a;
  const float4* b4 = (const float4*)b;
  float acc = 0.f;
#pragma unroll
  for (int q = 0; q < 8; ++q) {
    float4 x = a4[q], y = b4[q];
    acc += x.x * y.x + x.y * y.y + x.z * y.z + x.w * y.w;
  }
  return acc;
}

// ---------------- prep: folded W2P[c][o], B2P, zero out ----------------
__global__ __launch_bounds__(256) void prep_kernel(
    const float* __restrict__ Wm2, const float* __restrict__ bm2,
    const float* __restrict__ P0, const float* __restrict__ P2,
    float* __restrict__ ws, float* __restrict__ out) {
  int j = blockIdx.x * 256 + threadIdx.x;
  if (j < 2304) out[j] = 0.f;

  if (j < 12288) {
    const int c = j / 192, o = j % 192;
    const int s = o >> 5, u = o & 31;
    int k; const float* P; float sc;
    switch (s) {
      case 0: k = 0; P = P0;      sc = SC_Y0; break;
      case 1: k = 1; P = P2;      sc = SC_Y2; break;
      case 2: k = 2; P = P0 + 32; sc = SC_Y0; break;
      case 3: k = 4; P = P2 + 32; sc = SC_Y2; break;
      case 4: k = 6; P = P0 + 64; sc = SC_Y0; break;
      default: k = 8; P = P2 + 96; sc = SC_Y2; break;
    }
    float acc = dot32(Wm2 + c * 9216 + k * 1024 + u * 32, P);
    if (s == 1) acc += dot32(Wm2 + c * 9216 + 5 * 1024 + u * 32, P2 + 64);
    ws[OFF_W2P + j] = acc * sc;
  } else if (j < 12480) {
    const int o = j - 12288;
    const int s = o >> 5, u = o & 31;
    int k; const float* P; float sc;
    switch (s) {
      case 0: k = 0; P = P0;      sc = SC_Y0; break;
      case 1: k = 1; P = P2;      sc = SC_Y2; break;
      case 2: k = 2; P = P0 + 32; sc = SC_Y0; break;
      case 3: k = 4; P = P2 + 32; sc = SC_Y2; break;
      case 4: k = 6; P = P0 + 64; sc = SC_Y0; break;
      default: k = 8; P = P2 + 96; sc = SC_Y2; break;
    }
    float acc = dot32(bm2 + k * 1024 + u * 32, P);
    if (s == 1) acc += dot32(bm2 + 5 * 1024 + u * 32, P2 + 64);
    ws[OFF_B2P + o] = acc * sc;
  }
}

// ---------------- fused: 16-node tile (R8 structure) + 2u-grouped phase B ----------------
// Refined model (R8/R9/R10): VALU busy-time ~23us constant; wall = stall =
// loadcount x latency / hiding-waves. R10 proved <=2 blocks/CU starves hiding;
// R8's 4 blocks/CU works. This round = R8 with ONLY phase B remapped:
//   (1 node x 2 u, float2 weights): 344 loads/thread vs R8's 464, same 960 FMA.
// LDS 35456 B -> 4 blocks/CU: xp[16][484] + hi2[16][64] + sphs[16][6];
// Vt[16][193] overlays dead xp (193%32=1 -> phase-D reads <=2-way = free, m136).
// (256,4): 128-VGPR cap; R8 measured 64 VGPR, this adds ~0 (accs same size).
__global__ __launch_bounds__(256, 4) void fused_kernel(
    const float* __restrict__ xs_g, const float* __restrict__ xsph,
    const float* __restrict__ W0e, const float* __restrict__ W1o,
    const float* __restrict__ W2e,
    const float* __restrict__ Wm1, const float* __restrict__ bm1,
    const float* __restrict__ ws, const int* __restrict__ batch,
    float* __restrict__ out, const float norm2) {
  __shared__ __align__(16) float smem[8864];
  float (*xp)[484] = (float (*)[484])smem;                 // [0, 7744)
  float (*Vt)[193] = (float (*)[193])smem;                 // overlays xp after phase B
  float (*hi2)[64] = (float (*)[64])(smem + 7744);         // [7744, 8768)
  float (*sphs)[6] = (float (*)[6])(smem + 8768);          // [8768, 8864)

  const int tid = threadIdx.x;
  const int n0 = blockIdx.x * 16;

  // ---- stage-issue: x_sph (16x480 = 1920 float4) into registers (T14 split) ----
  float4 st[7];
  float4 st7;
#pragma unroll
  for (int k = 0; k < 7; ++k) {
    const int d = tid + k * 256;
    const int r = d / 120, c = d % 120;
    st[k] = *(const float4*)(xsph + (size_t)(n0 + r) * 480 + c * 4);
  }
  if (tid < 128) {
    const int d = tid + 1792;
    const int r = d / 120, c = d % 120;
    st7 = *(const float4*)(xsph + (size_t)(n0 + r) * 480 + c * 4);
  }

  // ---- phase 2 (hides staging latency): hidden = silu(x_scalar @ Wm1 + bm1) ----
  // thread = (n = tid>>4, channels c0..c0+3); float4 weight rows (R8 verbatim).
  {
    const int n = tid >> 4, c0 = (tid & 15) * 4;
    const float* xr = xs_g + (size_t)(n0 + n) * 128;
    float a0 = 0.f, a1 = 0.f, a2 = 0.f, a3 = 0.f;
#pragma unroll 4
    for (int mq = 0; mq < 32; ++mq) {
      const float4 xv = *(const float4*)(xr + mq * 4);   // broadcast per 16 lanes
      const float4 w0 = *(const float4*)(Wm1 + (mq * 4 + 0) * 64 + c0);
      const float4 w1 = *(const float4*)(Wm1 + (mq * 4 + 1) * 64 + c0);
      const float4 w2 = *(const float4*)(Wm1 + (mq * 4 + 2) * 64 + c0);
      const float4 w3 = *(const float4*)(Wm1 + (mq * 4 + 3) * 64 + c0);
      a0 += xv.x * w0.x + xv.y * w1.x + xv.z * w2.x + xv.w * w3.x;
      a1 += xv.x * w0.y + xv.y * w1.y + xv.z * w2.y + xv.w * w3.y;
      a2 += xv.x * w0.z + xv.y * w1.z + xv.z * w2.z + xv.w * w3.z;
      a3 += xv.x * w0.w + xv.y * w1.w + xv.z * w2.w + xv.w * w3.w;
    }
    const float4 bb = *(const float4*)(bm1 + c0);
    const float z0 = a0 + bb.x, z1 = a1 + bb.y, z2 = a2 + bb.z, z3 = a3 + bb.w;
    float4 s;
    s.x = z0 / (1.f + __expf(-z0));
    s.y = z1 / (1.f + __expf(-z1));
    s.z = z2 / (1.f + __expf(-z2));
    s.w = z3 / (1.f + __expf(-z3));
    *(float4*)&hi2[n][c0] = s;
  }

  // ---- stage-write: commit x_sph registers to LDS ----
#pragma unroll
  for (int k = 0; k < 7; ++k) {
    const int d = tid + k * 256;
    const int r = d / 120, c = d % 120;
    *(float4*)&xp[r][c * 4] = st[k];
  }
  if (tid < 128) {
    const int d = tid + 1792;
    const int r = d / 120, c = d % 120;
    *(float4*)&xp[r][c * 4] = st7;
  }
  __syncthreads();  // xp + hi2 ready

  // ---- phase B: h0/h1/h2; thread = (n = tid>>4, ug = tid&15 -> u0 = ug*2) ----
  const int n = tid >> 4, ug = tid & 15, u0 = ug * 2;
  const float* row = xp[n];
  float2 acc0 = {0.f, 0.f};
  float2 acc1[3];
  float2 acc2[5];

  // h0: K=128, 2 u via float2 weight rows (coalesced 128 B per 16 lanes)
#pragma unroll 4
  for (int mq = 0; mq < 32; ++mq) {
    const float4 xv = *(const float4*)(row + mq * 4);
#pragma unroll
    for (int r = 0; r < 4; ++r) {
      const float2 w = *(const float2*)(W0e + (mq * 4 + r) * 32 + u0);
      const float xr = COMP(xv, r);
      acc0.x += xr * w.x; acc0.y += xr * w.y;
    }
  }
  // h1: K=64, 3 comps
#pragma unroll
  for (int j = 0; j < 3; ++j) acc1[j] = make_float2(0.f, 0.f);
#pragma unroll 2
  for (int mq = 0; mq < 16; ++mq) {
    const float4 b0 = *(const float4*)(row + 128 + mq * 12);
    const float4 b1 = *(const float4*)(row + 128 + mq * 12 + 4);
    const float4 b2 = *(const float4*)(row + 128 + mq * 12 + 8);
    const float xa[12] = {b0.x, b0.y, b0.z, b0.w, b1.x, b1.y, b1.z, b1.w,
                          b2.x, b2.y, b2.z, b2.w};
#pragma unroll
    for (int mm = 0; mm < 4; ++mm) {
      const float2 w = *(const float2*)(W1o + (mq * 4 + mm) * 32 + u0);
#pragma unroll
      for (int j = 0; j < 3; ++j) {
        const float xr = xa[mm * 3 + j];
        acc1[j].x += xr * w.x; acc1[j].y += xr * w.y;
      }
    }
  }
  // h2: K=32, 5 comps
#pragma unroll
  for (int j = 0; j < 5; ++j) acc2[j] = make_float2(0.f, 0.f);
#pragma unroll 2
  for (int mq = 0; mq < 8; ++mq) {
    const float4 c0v = *(const float4*)(row + 320 + mq * 20);
    const float4 c1v = *(const float4*)(row + 320 + mq * 20 + 4);
    const float4 c2v = *(const float4*)(row + 320 + mq * 20 + 8);
    const float4 c3v = *(const float4*)(row + 320 + mq * 20 + 12);
    const float4 c4v = *(const float4*)(row + 320 + mq * 20 + 16);
    const float xa[20] = {c0v.x, c0v.y, c0v.z, c0v.w, c1v.x, c1v.y, c1v.z, c1v.w,
                          c2v.x, c2v.y, c2v.z, c2v.w, c3v.x, c3v.y, c3v.z, c3v.w,
                          c4v.x, c4v.y, c4v.z, c4v.w};
#pragma unroll
    for (int mm = 0; mm < 4; ++mm) {
      const float2 w = *(const float2*)(W2e + (mq * 4 + mm) * 32 + u0);
#pragma unroll
      for (int j = 0; j < 5; ++j) {
        const float xr = xa[mm * 5 + j];
        acc2[j].x += xr * w.x; acc2[j].y += xr * w.y;
      }
    }
  }
  __syncthreads();  // xp fully consumed -> Vt may overlay

  // ---- phase 3: V[n][o] = b2p[o] + sum_c hi2[n][c]*W2P[c][o]; 16 nodes/thread (R8) ----
  if (tid < 192) {
    const int o = tid;
    float acc[16];
    {
      const float b = ws[OFF_B2P + o];
#pragma unroll
      for (int nn = 0; nn < 16; ++nn) acc[nn] = b;
    }
    for (int c4 = 0; c4 < 64; c4 += 4) {
      const float w0 = ws[OFF_W2P + (c4 + 0) * 192 + o];  // coalesced; feeds 16 FMAs
      const float w1 = ws[OFF_W2P + (c4 + 1) * 192 + o];
      const float w2 = ws[OFF_W2P + (c4 + 2) * 192 + o];
      const float w3 = ws[OFF_W2P + (c4 + 3) * 192 + o];
#pragma unroll
      for (int nn = 0; nn < 16; ++nn) {
        const float4 h = *(const float4*)&hi2[nn][c4];    // broadcast
        acc[nn] += h.x * w0 + h.y * w1 + h.z * w2 + h.w * w3;
      }
    }
#pragma unroll
    for (int nn = 0; nn < 16; ++nn) Vt[nn][o] = acc[nn];
  }
  __syncthreads();  // Vt ready; h accs live in registers

  // ---- phase D: path math for 2 u's + in-thread sum + 16-lane shfl reduce ----
  {
    float y0s = 0.f;
    float y2s[5] = {0.f, 0.f, 0.f, 0.f, 0.f};
#pragma unroll
    for (int q = 0; q < 2; ++q) {
      const int u = u0 + q;
      const float* Vp = &Vt[n][u];
      const float v0 = Vp[0], v15 = Vp[32], v2 = Vp[64], v3 = Vp[96];
      const float v5 = Vp[128], v6 = Vp[160];

      const float h0 = (q == 0 ? acc0.x : acc0.y) * H0SC;
      const float h1a = (q == 0 ? acc1[0].x : acc1[0].y) * H1SC;
      const float h1b = (q == 0 ? acc1[1].x : acc1[1].y) * H1SC;
      const float h1c = (q == 0 ? acc1[2].x : acc1[2].y) * H1SC;
      float h2v[5];
#pragma unroll
      for (int jj = 0; jj < 5; ++jj)
        h2v[jj] = (q == 0 ? acc2[jj].x : acc2[jj].y) * H2SC;

      const float d11 = h1a * h1a + h1b * h1b + h1c * h1c;
      const float d22 = h2v[0] * h2v[0] + h2v[1] * h2v[1] + h2v[2] * h2v[2] +
                        h2v[3] * h2v[3] + h2v[4] * h2v[4];
      const float y0 = v0 * h0 * h0 + v2 * d11 * ISQRT3 + v5 * d22 * ISQRT5;

      const float o00 = h1a * h1a, o01 = h1a * h1b, o02 = h1a * h1c;
      const float o11 = h1b * h1b, o12 = h1b * h1c, o22 = h1c * h1c;
      const float t40 = TWOS2f * o01, t41 = TWOS2f * o12;
      const float t42 = S6f * (2.f * o22 - o00 - o11);
      const float t43 = TWOS2f * o02, t44 = S2f * (o00 - o11);

      const float A00 = -S6f * h2v[2] + S2f * h2v[4];
      const float A01 = S2f * h2v[0];
      const float A02 = S2f * h2v[3];
      const float A11 = -S6f * h2v[2] - S2f * h2v[4];
      const float A12 = S2f * h2v[1];
      const float A22 = TWOS6f * h2v[2];
      const float B00 = A00 * A00 + A01 * A01 + A02 * A02;
      const float B01 = A00 * A01 + A01 * A11 + A02 * A12;
      const float B02 = A00 * A02 + A01 * A12 + A02 * A22;
      const float B11 = A01 * A01 + A11 * A11 + A12 * A12;
      const float B12 = A01 * A02 + A11 * A12 + A12 * A22;
      const float B22 = A02 * A02 + A12 * A12 + A22 * A22;
      const float t80 = TWOS2f * B01, t81 = TWOS2f * B12;
      const float t82 = S6f * (2.f * B22 - B00 - B11);
      const float t83 = TWOS2f * B02, t84 = S2f * (B00 - B11);

      const float w15 = v15 * h0;
      const float v6n = v6 * norm2;
      y0s += y0;
      y2s[0] += w15 * h2v[0] + v3 * t40 + v6n * t80;
      y2s[1] += w15 * h2v[1] + v3 * t41 + v6n * t81;
      y2s[2] += w15 * h2v[2] + v3 * t42 + v6n * t82;
      y2s[3] += w15 * h2v[3] + v3 * t43 + v6n * t83;
      y2s[4] += w15 * h2v[4] + v3 * t44 + v6n * t84;
    }

#pragma unroll
    for (int off = 8; off > 0; off >>= 1) {
      y0s += __shfl_xor(y0s, off, 16);
#pragma unroll
      for (int r = 0; r < 5; ++r) y2s[r] += __shfl_xor(y2s[r], off, 16);
    }

    if (ug == 0) {
      sphs[n][0] = y0s;
#pragma unroll
      for (int r = 0; r < 5; ++r) sphs[n][1 + r] = y2s[r];
    }
  }
  __syncthreads();

  // ---- phase E: Q-contract + segment atomics over the 16-node tile ----
  if (tid < 9) {
    const float QW[9][6] = {
        {ISQRT3, 0.f, 0.f, -S6f, 0.f, S2f},
        {0.f, S2f, 0.f, 0.f, 0.f, 0.f},
        {0.f, 0.f, 0.f, 0.f, S2f, 0.f},
        {0.f, S2f, 0.f, 0.f, 0.f, 0.f},
        {ISQRT3, 0.f, 0.f, -S6f, 0.f, -S2f},
        {0.f, 0.f, S2f, 0.f, 0.f, 0.f},
        {0.f, 0.f, 0.f, 0.f, S2f, 0.f},
        {0.f, 0.f, S2f, 0.f, 0.f, 0.f},
        {ISQRT3, 0.f, 0.f, TWOS6f, 0.f, 0.f}};
    const int a = tid / 3, b = tid % 3;
    const int rolled = ((a + 1) % 3) * 3 + ((b + 1) % 3);
    const float c0 = QW[tid][0], c1 = QW[tid][1], c2 = QW[tid][2];
    const float c3 = QW[tid][3], c4 = QW[tid][4], c5 = QW[tid][5];
    int cur_g = batch[n0];
    float acc = 0.f;
#pragma unroll
    for (int q = 0; q < 16; ++q) {
      const int g = batch[n0 + q];
      const float val = c0 * sphs[q][0] + c1 * sphs[q][1] + c2 * sphs[q][2] +
                        c3 * sphs[q][3] + c4 * sphs[q][4] + c5 * sphs[q][5];
      if (g != cur_g) {
        atomicAdd(out + cur_g * 9 + rolled, acc);
        acc = 0.f;
        cur_g = g;
      }
      acc += val;
    }
    atomicAdd(out + cur_g * 9 + rolled, acc);
  }
}

extern "C" void kernel_launch(void* const* d_in, const int* in_sizes, int n_in,
                              void* d_out, int out_size, void* d_ws, size_t ws_size,
                              hipStream_t stream) {
  const float* x_scalar = (const float*)d_in[0];
  const float* x_sph    = (const float*)d_in[1];
  const int*   batch    = (const int*)d_in[2];
  const float* W0e      = (const float*)d_in[3];
  const float* W1o      = (const float*)d_in[4];
  const float* W2e      = (const float*)d_in[5];
  const float* Wm1      = (const float*)d_in[6];
  const float* bm1      = (const float*)d_in[7];
  const float* Wm2      = (const float*)d_in[8];
  const float* bm2      = (const float*)d_in[9];
  const float* P0       = (const float*)d_in[10];
  // P1 (d_in[11]) provably unused: C111/C221 antisymmetric vs h(x)h of same h.
  const float* P2       = (const float*)d_in[12];
  float* ws  = (float*)d_ws;
  float* out = (float*)d_out;

  if (ws_size < (size_t)WS_FLOATS * sizeof(float)) return;

  // host-side C222 normalization (pure CPU double math; = sqrt(12/7))
  double Q2[5][3][3] = {};
  const double s2d = 0.70710678118654752440, s6d = 0.40824829046386301637;
  Q2[0][0][1] = Q2[0][1][0] = s2d;
  Q2[1][1][2] = Q2[1][2][1] = s2d;
  Q2[2][0][0] = Q2[2][1][1] = -s6d; Q2[2][2][2] = 2.0 * s6d;
  Q2[3][0][2] = Q2[3][2][0] = s2d;
  Q2[4][0][0] = s2d; Q2[4][1][1] = -s2d;
  double ss = 0.0;
  for (int i = 0; i < 5; ++i)
    for (int jj = 0; jj < 5; ++jj) {
      double S[3][3];
      for (int a = 0; a < 3; ++a)
        for (int d = 0; d < 3; ++d) {
          double m1 = 0, m2 = 0;
          for (int b = 0; b < 3; ++b) {
            m1 += Q2[i][a][b] * Q2[jj][d][b];
            m2 += Q2[i][d][b] * Q2[jj][a][b];
          }
          S[a][d] = 0.5 * (m1 + m2);
        }
      double tr = (S[0][0] + S[1][1] + S[2][2]) / 3.0;
      S[0][0] -= tr; S[1][1] -= tr; S[2][2] -= tr;
      for (int kk = 0; kk < 5; ++kk) {
        double cc = 0;
        for (int a = 0; a < 3; ++a)
          for (int d = 0; d < 3; ++d) cc += Q2[kk][a][d] * S[a][d];
        ss += cc * cc;
      }
    }
  const float norm2 = (float)sqrt(5.0 / ss);

  prep_kernel<<<49, 256, 0, stream>>>(Wm2, bm2, P0, P2, ws, out);
  fused_kernel<<<1250, 256, 0, stream>>>(x_scalar, x_sph, W0e, W1o, W2e,
                                         Wm1, bm1, ws, batch, out, norm2);
}

// Round 12
// 165.518 us; speedup vs baseline: 1.0553x; 1.0063x over previous
//
#include <hip/hip_runtime.h>
#include <math.h>

// ---------------- workspace layout (float offsets) ----------------
// W2P folded (v1+v4 -> one column): [64][192], row-major [c][o] so lane o is coalesced.
#define OFF_W2P 0              // [64][192]
#define OFF_B2P 12288          // [192]
#define WS_FLOATS 12480

#define SC_Y0 0.0180421959121758f   // (1/sqrt(32))*(1/sqrt(96))
#define SC_Y2 0.015625f             // (1/sqrt(32))*(1/sqrt(128))
#define S2f 0.70710678118654752f
#define S6f 0.40824829046386302f
#define TWOS2f 1.41421356237309505f
#define TWOS6f 0.81649658092772603f
#define ISQRT3 0.57735026918962576f
#define ISQRT5 0.44721359549995794f
#define H0SC 0.08838834764831845f   // 1/sqrt(128)
#define H1SC 0.125f                 // 1/sqrt(64)
#define H2SC 0.17677669529663689f   // 1/sqrt(32)

__device__ static inline float dot32(const float* __restrict__ a,
                                     const float* __restrict__ b) {
  const float4* a4 = (const float4*)a;
  const float4* b4 = (const float4*)b;
  float acc = 0.f;
#pragma unroll
  for (int q = 0; q < 8; ++q) {
    float4 x = a4[q], y = b4[q];
    acc += x.x * y.x + x.y * y.y + x.z * y.z + x.w * y.w;
  }
  return acc;
}

// ---------------- prep: folded W2P[c][o], B2P, zero out ----------------
__global__ __launch_bounds__(256) void prep_kernel(
    const float* __restrict__ Wm2, const float* __restrict__ bm2,
    const float* __restrict__ P0, const float* __restrict__ P2,
    float* __restrict__ ws, float* __restrict__ out) {
  int j = blockIdx.x * 256 + threadIdx.x;
  if (j < 2304) out[j] = 0.f;

  if (j < 12288) {
    const int c = j / 192, o = j % 192;
    const int s = o >> 5, u = o & 31;
    int k; const float* P; float sc;
    switch (s) {
      case 0: k = 0; P = P0;      sc = SC_Y0; break;
      case 1: k = 1; P = P2;      sc = SC_Y2; break;
      case 2: k = 2; P = P0 + 32; sc = SC_Y0; break;
      case 3: k = 4; P = P2 + 32; sc = SC_Y2; break;
      case 4: k = 6; P = P0 + 64; sc = SC_Y0; break;
      default: k = 8; P = P2 + 96; sc = SC_Y2; break;
    }
    float acc = dot32(Wm2 + c * 9216 + k * 1024 + u * 32, P);
    if (s == 1) acc += dot32(Wm2 + c * 9216 + 5 * 1024 + u * 32, P2 + 64);
    ws[OFF_W2P + j] = acc * sc;
  } else if (j < 12480) {
    const int o = j - 12288;
    const int s = o >> 5, u = o & 31;
    int k; const float* P; float sc;
    switch (s) {
      case 0: k = 0; P = P0;      sc = SC_Y0; break;
      case 1: k = 1; P = P2;      sc = SC_Y2; break;
      case 2: k = 2; P = P0 + 32; sc = SC_Y0; break;
      case 3: k = 4; P = P2 + 32; sc = SC_Y2; break;
      case 4: k = 6; P = P0 + 64; sc = SC_Y0; break;
      default: k = 8; P = P2 + 96; sc = SC_Y2; break;
    }
    float acc = dot32(bm2 + k * 1024 + u * 32, P);
    if (s == 1) acc += dot32(bm2 + 5 * 1024 + u * 32, P2 + 64);
    ws[OFF_B2P + o] = acc * sc;
  }
}

// ---------------- fused: R8 structure + h0-unstaged for 6 blocks/CU ----------------
// R11 lesson: only GLOBAL loads drive stall, keep 2 independent node streams (R8 map).
// This round = R8 verbatim except:
//  - xp stages only x_sph cols [128,480) -> xp[16][352], LDS 27008 B -> 6 blocks/CU
//    (R8: 37.4KB -> 4). Full grid residency: 6*256=1536 >= 1250 blocks -> no tail.
//  - h0 reads its x slice from global (broadcast float4; 64/240 of phase-B x-reads).
//  - (256,6) forces VGPR <= 64 (m69: waves halve at 64) so 6 blocks are schedulable;
//    h1/h2 loops written A-block-then-B-block to keep peak live ~40 floats (no spill).
// Kill-switch: VGPR>64 or WRITE_SIZE balloon => spill => revert to R8.
__global__ __launch_bounds__(256, 6) void fused_kernel(
    const float* __restrict__ xs_g, const float* __restrict__ xsph,
    const float* __restrict__ W0e, const float* __restrict__ W1o,
    const float* __restrict__ W2e,
    const float* __restrict__ Wm1, const float* __restrict__ bm1,
    const float* __restrict__ ws, const int* __restrict__ batch,
    float* __restrict__ out, const float norm2) {
  __shared__ __align__(16) float smem[6752];
  float (*xp)[352] = (float (*)[352])smem;                 // x_sph cols [128,480)
  float (*Vt)[193] = (float (*)[193])smem;                 // overlays xp after phase B
  float (*hi2)[64] = (float (*)[64])(smem + 5632);         // [5632, 6656)
  float (*sphs)[6] = (float (*)[6])(smem + 6656);          // [6656, 6752)

  const int tid = threadIdx.x;
  const int n0 = blockIdx.x * 16;

  // ---- stage-issue: x_sph cols [128,480) = 16x88 float4 into registers (T14) ----
  float4 st[5];
  float4 st5;
#pragma unroll
  for (int k = 0; k < 5; ++k) {
    const int d = tid + k * 256;
    const int r = d / 88, c = d % 88;
    st[k] = *(const float4*)(xsph + (size_t)(n0 + r) * 480 + 128 + c * 4);
  }
  if (tid < 128) {
    const int d = 1280 + tid;
    const int r = d / 88, c = d % 88;
    st5 = *(const float4*)(xsph + (size_t)(n0 + r) * 480 + 128 + c * 4);
  }

  // ---- phase 2 (hides staging latency): hidden = silu(x_scalar @ Wm1 + bm1) ----
  // thread = (n = tid>>4, channels c0..c0+3); float4 weight rows (R8 verbatim).
  {
    const int n = tid >> 4, c0 = (tid & 15) * 4;
    const float* xr = xs_g + (size_t)(n0 + n) * 128;
    float a0 = 0.f, a1 = 0.f, a2 = 0.f, a3 = 0.f;
#pragma unroll 4
    for (int mq = 0; mq < 32; ++mq) {
      const float4 xv = *(const float4*)(xr + mq * 4);   // broadcast per 16 lanes
      const float4 w0 = *(const float4*)(Wm1 + (mq * 4 + 0) * 64 + c0);
      const float4 w1 = *(const float4*)(Wm1 + (mq * 4 + 1) * 64 + c0);
      const float4 w2 = *(const float4*)(Wm1 + (mq * 4 + 2) * 64 + c0);
      const float4 w3 = *(const float4*)(Wm1 + (mq * 4 + 3) * 64 + c0);
      a0 += xv.x * w0.x + xv.y * w1.x + xv.z * w2.x + xv.w * w3.x;
      a1 += xv.x * w0.y + xv.y * w1.y + xv.z * w2.y + xv.w * w3.y;
      a2 += xv.x * w0.z + xv.y * w1.z + xv.z * w2.z + xv.w * w3.z;
      a3 += xv.x * w0.w + xv.y * w1.w + xv.z * w2.w + xv.w * w3.w;
    }
    const float4 bb = *(const float4*)(bm1 + c0);
    const float z0 = a0 + bb.x, z1 = a1 + bb.y, z2 = a2 + bb.z, z3 = a3 + bb.w;
    float4 s;
    s.x = z0 / (1.f + __expf(-z0));
    s.y = z1 / (1.f + __expf(-z1));
    s.z = z2 / (1.f + __expf(-z2));
    s.w = z3 / (1.f + __expf(-z3));
    *(float4*)&hi2[n][c0] = s;
  }

  // ---- stage-write: commit x_sph registers to LDS ----
#pragma unroll
  for (int k = 0; k < 5; ++k) {
    const int d = tid + k * 256;
    const int r = d / 88, c = d % 88;
    *(float4*)&xp[r][c * 4] = st[k];
  }
  if (tid < 128) {
    const int d = 1280 + tid;
    const int r = d / 88, c = d % 88;
    *(float4*)&xp[r][c * 4] = st5;
  }
  __syncthreads();  // xp + hi2 ready

  // ---- phase B: h0/h1/h2 for TWO nodes per thread (R8 mapping) ----
  const int u = tid & 31, ni = tid >> 5;     // nodes ni and ni+8
  const float* rowA = xp[ni];
  const float* rowB = xp[ni + 8];
  const float* gA = xsph + (size_t)(n0 + ni) * 480;        // h0 slice from global
  const float* gB = xsph + (size_t)(n0 + ni + 8) * 480;

  float h0A, h0B;
  {
    float aA = 0.f, aB = 0.f;
#pragma unroll 4
    for (int mq = 0; mq < 32; ++mq) {
      const float4 xa = *(const float4*)(gA + mq * 4);     // broadcast per half-wave
      const float4 xb = *(const float4*)(gB + mq * 4);
      const float w0 = W0e[(mq * 4 + 0) * 32 + u];         // coalesced; feeds 2 FMAs
      const float w1 = W0e[(mq * 4 + 1) * 32 + u];
      const float w2 = W0e[(mq * 4 + 2) * 32 + u];
      const float w3 = W0e[(mq * 4 + 3) * 32 + u];
      aA += xa.x * w0 + xa.y * w1 + xa.z * w2 + xa.w * w3;
      aB += xb.x * w0 + xb.y * w1 + xb.z * w2 + xb.w * w3;
    }
    h0A = aA * H0SC; h0B = aB * H0SC;
  }

  float h1A[3], h1B[3];
  {
    float aA[3] = {0.f, 0.f, 0.f}, aB[3] = {0.f, 0.f, 0.f};
#pragma unroll 2
    for (int mq = 0; mq < 16; ++mq) {
      const float w0 = W1o[(mq * 4 + 0) * 32 + u];
      const float w1 = W1o[(mq * 4 + 1) * 32 + u];
      const float w2 = W1o[(mq * 4 + 2) * 32 + u];
      const float w3 = W1o[(mq * 4 + 3) * 32 + u];
      {  // A block (keeps peak live low for the 64-VGPR cap)
        const float4 b0 = *(const float4*)(rowA + mq * 12);
        const float4 b1 = *(const float4*)(rowA + mq * 12 + 4);
        const float4 b2 = *(const float4*)(rowA + mq * 12 + 8);
        aA[0] += b0.x * w0 + b0.w * w1 + b1.z * w2 + b2.y * w3;
        aA[1] += b0.y * w0 + b1.x * w1 + b1.w * w2 + b2.z * w3;
        aA[2] += b0.z * w0 + b1.y * w1 + b2.x * w2 + b2.w * w3;
      }
      {  // B block
        const float4 b0 = *(const float4*)(rowB + mq * 12);
        const float4 b1 = *(const float4*)(rowB + mq * 12 + 4);
        const float4 b2 = *(const float4*)(rowB + mq * 12 + 8);
        aB[0] += b0.x * w0 + b0.w * w1 + b1.z * w2 + b2.y * w3;
        aB[1] += b0.y * w0 + b1.x * w1 + b1.w * w2 + b2.z * w3;
        aB[2] += b0.z * w0 + b1.y * w1 + b2.x * w2 + b2.w * w3;
      }
    }
#pragma unroll
    for (int j = 0; j < 3; ++j) { h1A[j] = aA[j] * H1SC; h1B[j] = aB[j] * H1SC; }
  }

  float h2A[5], h2B[5];
  {
    float aA[5] = {0.f, 0.f, 0.f, 0.f, 0.f}, aB[5] = {0.f, 0.f, 0.f, 0.f, 0.f};
#pragma unroll 2
    for (int mq = 0; mq < 8; ++mq) {
      const float w0 = W2e[(mq * 4 + 0) * 32 + u];
      const float w1 = W2e[(mq * 4 + 1) * 32 + u];
      const float w2 = W2e[(mq * 4 + 2) * 32 + u];
      const float w3 = W2e[(mq * 4 + 3) * 32 + u];
      {  // A block
        const float4 c0 = *(const float4*)(rowA + 192 + mq * 20);
        const float4 c1 = *(const float4*)(rowA + 192 + mq * 20 + 4);
        const float4 c2 = *(const float4*)(rowA + 192 + mq * 20 + 8);
        const float4 c3 = *(const float4*)(rowA + 192 + mq * 20 + 12);
        const float4 c4 = *(const float4*)(rowA + 192 + mq * 20 + 16);
        aA[0] += c0.x * w0 + c1.y * w1 + c2.z * w2 + c3.w * w3;
        aA[1] += c0.y * w0 + c1.z * w1 + c2.w * w2 + c4.x * w3;
        aA[2] += c0.z * w0 + c1.w * w1 + c3.x * w2 + c4.y * w3;
        aA[3] += c0.w * w0 + c2.x * w1 + c3.y * w2 + c4.z * w3;
        aA[4] += c1.x * w0 + c2.y * w1 + c3.z * w2 + c4.w * w3;
      }
      {  // B block
        const float4 c0 = *(const float4*)(rowB + 192 + mq * 20);
        const float4 c1 = *(const float4*)(rowB + 192 + mq * 20 + 4);
        const float4 c2 = *(const float4*)(rowB + 192 + mq * 20 + 8);
        const float4 c3 = *(const float4*)(rowB + 192 + mq * 20 + 12);
        const float4 c4 = *(const float4*)(rowB + 192 + mq * 20 + 16);
        aB[0] += c0.x * w0 + c1.y * w1 + c2.z * w2 + c3.w * w3;
        aB[1] += c0.y * w0 + c1.z * w1 + c2.w * w2 + c4.x * w3;
        aB[2] += c0.z * w0 + c1.w * w1 + c3.x * w2 + c4.y * w3;
        aB[3] += c0.w * w0 + c2.x * w1 + c3.y * w2 + c4.z * w3;
        aB[4] += c1.x * w0 + c2.y * w1 + c3.z * w2 + c4.w * w3;
      }
    }
#pragma unroll
    for (int j = 0; j < 5; ++j) { h2A[j] = aA[j] * H2SC; h2B[j] = aB[j] * H2SC; }
  }
  __syncthreads();  // xp fully consumed -> Vt may overlay

  // ---- phase 3: V[n][o] = b2p[o] + sum_c hi2[n][c]*W2P[c][o]; 16 nodes/thread (R8) ----
  if (tid < 192) {
    const int o = tid;
    float acc[16];
    {
      const float b = ws[OFF_B2P + o];
#pragma unroll
      for (int nn = 0; nn < 16; ++nn) acc[nn] = b;
    }
    for (int c4 = 0; c4 < 64; c4 += 4) {
      const float w0 = ws[OFF_W2P + (c4 + 0) * 192 + o];  // coalesced; feeds 16 FMAs
      const float w1 = ws[OFF_W2P + (c4 + 1) * 192 + o];
      const float w2 = ws[OFF_W2P + (c4 + 2) * 192 + o];
      const float w3 = ws[OFF_W2P + (c4 + 3) * 192 + o];
#pragma unroll
      for (int nn = 0; nn < 16; ++nn) {
        const float4 h = *(const float4*)&hi2[nn][c4];    // broadcast
        acc[nn] += h.x * w0 + h.y * w1 + h.z * w2 + h.w * w3;
      }
    }
#pragma unroll
    for (int nn = 0; nn < 16; ++nn) Vt[nn][o] = acc[nn];
  }
  __syncthreads();  // Vt ready; h accs live in registers

  // ---- phase D: path math + u-reduction for both nodes (R8 verbatim) ----
#pragma unroll
  for (int it = 0; it < 2; ++it) {
    const int ln = ni + 8 * it;
    const float h0 = (it == 0) ? h0A : h0B;
    const float h1a = (it == 0) ? h1A[0] : h1B[0];
    const float h1b = (it == 0) ? h1A[1] : h1B[1];
    const float h1c = (it == 0) ? h1A[2] : h1B[2];
    float h2v[5];
#pragma unroll
    for (int j = 0; j < 5; ++j) h2v[j] = (it == 0) ? h2A[j] : h2B[j];

    const float* Vp = &Vt[ln][u];
    const float v0 = Vp[0], v15 = Vp[32], v2 = Vp[64], v3 = Vp[96];
    const float v5 = Vp[128], v6 = Vp[160];

    const float d11 = h1a * h1a + h1b * h1b + h1c * h1c;
    const float d22 = h2v[0] * h2v[0] + h2v[1] * h2v[1] + h2v[2] * h2v[2] +
                      h2v[3] * h2v[3] + h2v[4] * h2v[4];
    float y0 = v0 * h0 * h0 + v2 * d11 * ISQRT3 + v5 * d22 * ISQRT5;

    const float o00 = h1a * h1a, o01 = h1a * h1b, o02 = h1a * h1c;
    const float o11 = h1b * h1b, o12 = h1b * h1c, o22 = h1c * h1c;
    const float t40 = TWOS2f * o01, t41 = TWOS2f * o12;
    const float t42 = S6f * (2.f * o22 - o00 - o11);
    const float t43 = TWOS2f * o02, t44 = S2f * (o00 - o11);

    const float A00 = -S6f * h2v[2] + S2f * h2v[4];
    const float A01 = S2f * h2v[0];
    const float A02 = S2f * h2v[3];
    const float A11 = -S6f * h2v[2] - S2f * h2v[4];
    const float A12 = S2f * h2v[1];
    const float A22 = TWOS6f * h2v[2];
    const float B00 = A00 * A00 + A01 * A01 + A02 * A02;
    const float B01 = A00 * A01 + A01 * A11 + A02 * A12;
    const float B02 = A00 * A02 + A01 * A12 + A02 * A22;
    const float B11 = A01 * A01 + A11 * A11 + A12 * A12;
    const float B12 = A01 * A02 + A11 * A12 + A12 * A22;
    const float B22 = A02 * A02 + A12 * A12 + A22 * A22;
    const float t80 = TWOS2f * B01, t81 = TWOS2f * B12;
    const float t82 = S6f * (2.f * B22 - B00 - B11);
    const float t83 = TWOS2f * B02, t84 = S2f * (B00 - B11);

    const float w15 = v15 * h0;
    const float v6n = v6 * norm2;
    float y2r[5];
    y2r[0] = w15 * h2v[0] + v3 * t40 + v6n * t80;
    y2r[1] = w15 * h2v[1] + v3 * t41 + v6n * t81;
    y2r[2] = w15 * h2v[2] + v3 * t42 + v6n * t82;
    y2r[3] = w15 * h2v[3] + v3 * t43 + v6n * t83;
    y2r[4] = w15 * h2v[4] + v3 * t44 + v6n * t84;

#pragma unroll
    for (int off = 16; off > 0; off >>= 1) {
      y0 += __shfl_xor(y0, off, 32);
#pragma unroll
      for (int r = 0; r < 5; ++r) y2r[r] += __shfl_xor(y2r[r], off, 32);
    }

    if (u == 0) {
      sphs[ln][0] = y0;
#pragma unroll
      for (int r = 0; r < 5; ++r) sphs[ln][1 + r] = y2r[r];
    }
  }
  __syncthreads();

  // ---- phase E: Q-contract + segment atomics over the 16-node tile ----
  if (tid < 9) {
    const float QW[9][6] = {
        {ISQRT3, 0.f, 0.f, -S6f, 0.f, S2f},
        {0.f, S2f, 0.f, 0.f, 0.f, 0.f},
        {0.f, 0.f, 0.f, 0.f, S2f, 0.f},
        {0.f, S2f, 0.f, 0.f, 0.f, 0.f},
        {ISQRT3, 0.f, 0.f, -S6f, 0.f, -S2f},
        {0.f, 0.f, S2f, 0.f, 0.f, 0.f},
        {0.f, 0.f, 0.f, 0.f, S2f, 0.f},
        {0.f, 0.f, S2f, 0.f, 0.f, 0.f},
        {ISQRT3, 0.f, 0.f, TWOS6f, 0.f, 0.f}};
    const int a = tid / 3, b = tid % 3;
    const int rolled = ((a + 1) % 3) * 3 + ((b + 1) % 3);
    const float c0 = QW[tid][0], c1 = QW[tid][1], c2 = QW[tid][2];
    const float c3 = QW[tid][3], c4 = QW[tid][4], c5 = QW[tid][5];
    int cur_g = batch[n0];
    float acc = 0.f;
#pragma unroll
    for (int q = 0; q < 16; ++q) {
      const int g = batch[n0 + q];
      const float val = c0 * sphs[q][0] + c1 * sphs[q][1] + c2 * sphs[q][2] +
                        c3 * sphs[q][3] + c4 * sphs[q][4] + c5 * sphs[q][5];
      if (g != cur_g) {
        atomicAdd(out + cur_g * 9 + rolled, acc);
        acc = 0.f;
        cur_g = g;
      }
      acc += val;
    }
    atomicAdd(out + cur_g * 9 + rolled, acc);
  }
}

extern "C" void kernel_launch(void* const* d_in, const int* in_sizes, int n_in,
                              void* d_out, int out_size, void* d_ws, size_t ws_size,
                              hipStream_t stream) {
  const float* x_scalar = (const float*)d_in[0];
  const float* x_sph    = (const float*)d_in[1];
  const int*   batch    = (const int*)d_in[2];
  const float* W0e      = (const float*)d_in[3];
  const float* W1o      = (const float*)d_in[4];
  const float* W2e      = (const float*)d_in[5];
  const float* Wm1      = (const float*)d_in[6];
  const float* bm1      = (const float*)d_in[7];
  const float* Wm2      = (const float*)d_in[8];
  const float* bm2      = (const float*)d_in[9];
  const float* P0       = (const float*)d_in[10];
  // P1 (d_in[11]) provably unused: C111/C221 antisymmetric vs h(x)h of same h.
  const float* P2       = (const float*)d_in[12];
  float* ws  = (float*)d_ws;
  float* out = (float*)d_out;

  if (ws_size < (size_t)WS_FLOATS * sizeof(float)) return;

  // host-side C222 normalization (pure CPU double math; = sqrt(12/7))
  double Q2[5][3][3] = {};
  const double s2d = 0.70710678118654752440, s6d = 0.40824829046386301637;
  Q2[0][0][1] = Q2[0][1][0] = s2d;
  Q2[1][1][2] = Q2[1][2][1] = s2d;
  Q2[2][0][0] = Q2[2][1][1] = -s6d; Q2[2][2][2] = 2.0 * s6d;
  Q2[3][0][2] = Q2[3][2][0] = s2d;
  Q2[4][0][0] = s2d; Q2[4][1][1] = -s2d;
  double ss = 0.0;
  for (int i = 0; i < 5; ++i)
    for (int jj = 0; jj < 5; ++jj) {
      double S[3][3];
      for (int a = 0; a < 3; ++a)
        for (int d = 0; d < 3; ++d) {
          double m1 = 0, m2 = 0;
          for (int b = 0; b < 3; ++b) {
            m1 += Q2[i][a][b] * Q2[jj][d][b];
            m2 += Q2[i][d][b] * Q2[jj][a][b];
          }
          S[a][d] = 0.5 * (m1 + m2);
        }
      double tr = (S[0][0] + S[1][1] + S[2][2]) / 3.0;
      S[0][0] -= tr; S[1][1] -= tr; S[2][2] -= tr;
      for (int kk = 0; kk < 5; ++kk) {
        double cc = 0;
        for (int a = 0; a < 3; ++a)
          for (int d = 0; d < 3; ++d) cc += Q2[kk][a][d] * S[a][d];
        ss += cc * cc;
      }
    }
  const float norm2 = (float)sqrt(5.0 / ss);

  prep_kernel<<<49, 256, 0, stream>>>(Wm2, bm2, P0, P2, ws, out);
  fused_kernel<<<1250, 256, 0, stream>>>(x_scalar, x_sph, W0e, W1o, W2e,
                                         Wm1, bm1, ws, batch, out, norm2);
}

// Round 13
// 152.374 us; speedup vs baseline: 1.1463x; 1.0863x over previous
//
#include <hip/hip_runtime.h>
#include <math.h>

// ---------------- workspace layout (float offsets) ----------------
// W2P folded (v1+v4 -> one column): [64][192], row-major [c][o] so lane o is coalesced.
#define OFF_W2P 0              // [64][192]
#define OFF_B2P 12288          // [192]
#define WS_FLOATS 12480

#define SC_Y0 0.0180421959121758f   // (1/sqrt(32))*(1/sqrt(96))
#define SC_Y2 0.015625f             // (1/sqrt(32))*(1/sqrt(128))
#define S2f 0.70710678118654752f
#define S6f 0.40824829046386302f
#define TWOS2f 1.41421356237309505f
#define TWOS6f 0.81649658092772603f
#define ISQRT3 0.57735026918962576f
#define ISQRT5 0.44721359549995794f
#define H0SC 0.08838834764831845f   // 1/sqrt(128)
#define H1SC 0.125f                 // 1/sqrt(64)
#define H2SC 0.17677669529663689f   // 1/sqrt(32)

__device__ static inline float dot32(const float* __restrict__ a,
                                     const float* __restrict__ b) {
  const float4* a4 = (const float4*)a;
  const float4* b4 = (const float4*)b;
  float acc = 0.f;
#pragma unroll
  for (int q = 0; q < 8; ++q) {
    float4 x = a4[q], y = b4[q];
    acc += x.x * y.x + x.y * y.y + x.z * y.z + x.w * y.w;
  }
  return acc;
}

// ---------------- prep: folded W2P[c][o], B2P, zero out ----------------
__global__ __launch_bounds__(256) void prep_kernel(
    const float* __restrict__ Wm2, const float* __restrict__ bm2,
    const float* __restrict__ P0, const float* __restrict__ P2,
    float* __restrict__ ws, float* __restrict__ out) {
  int j = blockIdx.x * 256 + threadIdx.x;
  if (j < 2304) out[j] = 0.f;

  if (j < 12288) {
    const int c = j / 192, o = j % 192;
    const int s = o >> 5, u = o & 31;
    int k; const float* P; float sc;
    switch (s) {
      case 0: k = 0; P = P0;      sc = SC_Y0; break;
      case 1: k = 1; P = P2;      sc = SC_Y2; break;
      case 2: k = 2; P = P0 + 32; sc = SC_Y0; break;
      case 3: k = 4; P = P2 + 32; sc = SC_Y2; break;
      case 4: k = 6; P = P0 + 64; sc = SC_Y0; break;
      default: k = 8; P = P2 + 96; sc = SC_Y2; break;
    }
    float acc = dot32(Wm2 + c * 9216 + k * 1024 + u * 32, P);
    if (s == 1) acc += dot32(Wm2 + c * 9216 + 5 * 1024 + u * 32, P2 + 64);
    ws[OFF_W2P + j] = acc * sc;
  } else if (j < 12480) {
    const int o = j - 12288;
    const int s = o >> 5, u = o & 31;
    int k; const float* P; float sc;
    switch (s) {
      case 0: k = 0; P = P0;      sc = SC_Y0; break;
      case 1: k = 1; P = P2;      sc = SC_Y2; break;
      case 2: k = 2; P = P0 + 32; sc = SC_Y0; break;
      case 3: k = 4; P = P2 + 32; sc = SC_Y2; break;
      case 4: k = 6; P = P0 + 64; sc = SC_Y0; break;
      default: k = 8; P = P2 + 96; sc = SC_Y2; break;
    }
    float acc = dot32(bm2 + k * 1024 + u * 32, P);
    if (s == 1) acc += dot32(bm2 + 5 * 1024 + u * 32, P2 + 64);
    ws[OFF_B2P + o] = acc * sc;
  }
}

// ---------------- fused: 16-node tile, 2-node/thread weight reuse (R8, session best) ----------------
// Governing model (R7-R12 evidence): VALU busy-time constant ~24us; wall time = stall =
// global-load count x latency / hiding-waves. This point is the measured optimum:
//   - 2-node/thread phase B: every weight load feeds 2 FMAs, 2 independent ILP streams
//     (R11: 1-node/2-u variant regressed; R9: half-block deployment regressed)
//   - 4 blocks/CU residency (R10: 2 blocks/CU starves hiding, regressed)
//   - VGPR 64 with NO spill under (256,4) cap (R2/R4/R12: tighter bounds spill, regress)
//   - xp LDS staging of x_sph (R6: un-staging costs ~40us; R12: partial un-staging also lost)
// LDS 37.2 KB: xp[16][512] + hi2[16][64] + sphs[16][6]; Vt[16][192] overlays dead xp.
// T14 split staging (issue regs early, ds_write after phase 2 hides HBM latency).
__global__ __launch_bounds__(256, 4) void fused_kernel(
    const float* __restrict__ xs_g, const float* __restrict__ xsph,
    const float* __restrict__ W0e, const float* __restrict__ W1o,
    const float* __restrict__ W2e,
    const float* __restrict__ Wm1, const float* __restrict__ bm1,
    const float* __restrict__ ws, const int* __restrict__ batch,
    float* __restrict__ out, const float norm2) {
  __shared__ __align__(16) float smem[9312];
  float (*xp)[512] = (float (*)[512])smem;          // [16][512], data in [0,480)
  float (*Vt)[192] = (float (*)[192])smem;          // overlays xp after phase B
  float (*hi2)[64] = (float (*)[64])(smem + 8192);
  float (*sphs)[6] = (float (*)[6])(smem + 9216);

  const int tid = threadIdx.x;
  const int n0 = blockIdx.x * 16;

  // ---- stage-issue: x_sph (16x480 = 1920 float4) into registers; 7-8 per thread ----
  float4 st[7];
  float4 st7;
#pragma unroll
  for (int k = 0; k < 7; ++k) {
    const int d = tid + k * 256;                 // float4 index into 16x120 data
    const int r = d / 120, c = d % 120;
    st[k] = *(const float4*)(xsph + (size_t)(n0 + r) * 480 + c * 4);
  }
  if (tid < 128) {
    const int d = tid + 1792;
    const int r = d / 120, c = d % 120;
    st7 = *(const float4*)(xsph + (size_t)(n0 + r) * 480 + c * 4);
  }

  // ---- phase 2 (hides staging latency): hidden = silu(x_scalar @ Wm1 + bm1) ----
  // thread = (n = tid>>4, channels c0..c0+3); float4 weight rows, 512 FMA / 160 loads.
  {
    const int n = tid >> 4, c0 = (tid & 15) * 4;
    const float* xr = xs_g + (size_t)(n0 + n) * 128;
    float a0 = 0.f, a1 = 0.f, a2 = 0.f, a3 = 0.f;
#pragma unroll 4
    for (int mq = 0; mq < 32; ++mq) {
      const float4 xv = *(const float4*)(xr + mq * 4);   // broadcast per 16 lanes
      const float4 w0 = *(const float4*)(Wm1 + (mq * 4 + 0) * 64 + c0);
      const float4 w1 = *(const float4*)(Wm1 + (mq * 4 + 1) * 64 + c0);
      const float4 w2 = *(const float4*)(Wm1 + (mq * 4 + 2) * 64 + c0);
      const float4 w3 = *(const float4*)(Wm1 + (mq * 4 + 3) * 64 + c0);
      a0 += xv.x * w0.x + xv.y * w1.x + xv.z * w2.x + xv.w * w3.x;
      a1 += xv.x * w0.y + xv.y * w1.y + xv.z * w2.y + xv.w * w3.y;
      a2 += xv.x * w0.z + xv.y * w1.z + xv.z * w2.z + xv.w * w3.z;
      a3 += xv.x * w0.w + xv.y * w1.w + xv.z * w2.w + xv.w * w3.w;
    }
    const float4 bb = *(const float4*)(bm1 + c0);
    const float z0 = a0 + bb.x, z1 = a1 + bb.y, z2 = a2 + bb.z, z3 = a3 + bb.w;
    float4 s;
    s.x = z0 / (1.f + __expf(-z0));
    s.y = z1 / (1.f + __expf(-z1));
    s.z = z2 / (1.f + __expf(-z2));
    s.w = z3 / (1.f + __expf(-z3));
    *(float4*)&hi2[n][c0] = s;
  }

  // ---- stage-write: commit x_sph registers to LDS (padded rows, stride 512) ----
#pragma unroll
  for (int k = 0; k < 7; ++k) {
    const int d = tid + k * 256;
    const int r = d / 120, c = d % 120;
    *(float4*)&xp[r][c * 4] = st[k];
  }
  if (tid < 128) {
    const int d = tid + 1792;
    const int r = d / 120, c = d % 120;
    *(float4*)&xp[r][c * 4] = st7;
  }
  __syncthreads();  // xp + hi2 ready

  // ---- phase B: h0/h1/h2 for TWO nodes per thread (weight reuse x2) ----
  const int u = tid & 31, ni = tid >> 5;     // nodes ni and ni+8
  const float* rowA = xp[ni];
  const float* rowB = xp[ni + 8];

  float h0A, h0B;
  {
    float aA = 0.f, aB = 0.f;
#pragma unroll 4
    for (int mq = 0; mq < 32; ++mq) {
      const float4 xa = *(const float4*)(rowA + mq * 4);
      const float4 xb = *(const float4*)(rowB + mq * 4);
      const float w0 = W0e[(mq * 4 + 0) * 32 + u];   // coalesced; feeds 2 FMAs
      const float w1 = W0e[(mq * 4 + 1) * 32 + u];
      const float w2 = W0e[(mq * 4 + 2) * 32 + u];
      const float w3 = W0e[(mq * 4 + 3) * 32 + u];
      aA += xa.x * w0 + xa.y * w1 + xa.z * w2 + xa.w * w3;
      aB += xb.x * w0 + xb.y * w1 + xb.z * w2 + xb.w * w3;
    }
    h0A = aA * H0SC; h0B = aB * H0SC;
  }

  float h1A[3], h1B[3];
  {
    float aA[3] = {0.f, 0.f, 0.f}, aB[3] = {0.f, 0.f, 0.f};
#pragma unroll 2
    for (int mq = 0; mq < 16; ++mq) {
      const float4 a0 = *(const float4*)(rowA + 128 + mq * 12);
      const float4 a1 = *(const float4*)(rowA + 128 + mq * 12 + 4);
      const float4 a2 = *(const float4*)(rowA + 128 + mq * 12 + 8);
      const float4 b0 = *(const float4*)(rowB + 128 + mq * 12);
      const float4 b1 = *(const float4*)(rowB + 128 + mq * 12 + 4);
      const float4 b2 = *(const float4*)(rowB + 128 + mq * 12 + 8);
      const float xa[12] = {a0.x, a0.y, a0.z, a0.w, a1.x, a1.y, a1.z, a1.w,
                            a2.x, a2.y, a2.z, a2.w};
      const float xb[12] = {b0.x, b0.y, b0.z, b0.w, b1.x, b1.y, b1.z, b1.w,
                            b2.x, b2.y, b2.z, b2.w};
#pragma unroll
      for (int mm = 0; mm < 4; ++mm) {
        const float w = W1o[(mq * 4 + mm) * 32 + u];
#pragma unroll
        for (int j = 0; j < 3; ++j) {
          aA[j] += xa[mm * 3 + j] * w;
          aB[j] += xb[mm * 3 + j] * w;
        }
      }
    }
#pragma unroll
    for (int j = 0; j < 3; ++j) { h1A[j] = aA[j] * H1SC; h1B[j] = aB[j] * H1SC; }
  }

  float h2A[5], h2B[5];
  {
    float aA[5] = {0.f, 0.f, 0.f, 0.f, 0.f}, aB[5] = {0.f, 0.f, 0.f, 0.f, 0.f};
#pragma unroll 2
    for (int mq = 0; mq < 8; ++mq) {
      const float4 a0 = *(const float4*)(rowA + 320 + mq * 20);
      const float4 a1 = *(const float4*)(rowA + 320 + mq * 20 + 4);
      const float4 a2 = *(const float4*)(rowA + 320 + mq * 20 + 8);
      const float4 a3 = *(const float4*)(rowA + 320 + mq * 20 + 12);
      const float4 a4 = *(const float4*)(rowA + 320 + mq * 20 + 16);
      const float4 b0 = *(const float4*)(rowB + 320 + mq * 20);
      const float4 b1 = *(const float4*)(rowB + 320 + mq * 20 + 4);
      const float4 b2 = *(const float4*)(rowB + 320 + mq * 20 + 8);
      const float4 b3 = *(const float4*)(rowB + 320 + mq * 20 + 12);
      const float4 b4 = *(const float4*)(rowB + 320 + mq * 20 + 16);
      const float xa[20] = {a0.x, a0.y, a0.z, a0.w, a1.x, a1.y, a1.z, a1.w,
                            a2.x, a2.y, a2.z, a2.w, a3.x, a3.y, a3.z, a3.w,
                            a4.x, a4.y, a4.z, a4.w};
      const float xb[20] = {b0.x, b0.y, b0.z, b0.w, b1.x, b1.y, b1.z, b1.w,
                            b2.x, b2.y, b2.z, b2.w, b3.x, b3.y, b3.z, b3.w,
                            b4.x, b4.y, b4.z, b4.w};
#pragma unroll
      for (int mm = 0; mm < 4; ++mm) {
        const float w = W2e[(mq * 4 + mm) * 32 + u];
#pragma unroll
        for (int j = 0; j < 5; ++j) {
          aA[j] += xa[mm * 5 + j] * w;
          aB[j] += xb[mm * 5 + j] * w;
        }
      }
    }
#pragma unroll
    for (int j = 0; j < 5; ++j) { h2A[j] = aA[j] * H2SC; h2B[j] = aB[j] * H2SC; }
  }
  __syncthreads();  // xp fully consumed -> Vt may overlay

  // ---- phase 3: V[n][o] = b2p[o] + sum_c hi2[n][c]*W2P[c][o]; 16 nodes/thread ----
  if (tid < 192) {
    const int o = tid;
    float acc[16];
    {
      const float b = ws[OFF_B2P + o];
#pragma unroll
      for (int n = 0; n < 16; ++n) acc[n] = b;
    }
    for (int c4 = 0; c4 < 64; c4 += 4) {
      const float w0 = ws[OFF_W2P + (c4 + 0) * 192 + o];  // coalesced; feeds 16 FMAs
      const float w1 = ws[OFF_W2P + (c4 + 1) * 192 + o];
      const float w2 = ws[OFF_W2P + (c4 + 2) * 192 + o];
      const float w3 = ws[OFF_W2P + (c4 + 3) * 192 + o];
#pragma unroll
      for (int n = 0; n < 16; ++n) {
        const float4 h = *(const float4*)&hi2[n][c4];     // broadcast
        acc[n] += h.x * w0 + h.y * w1 + h.z * w2 + h.w * w3;
      }
    }
#pragma unroll
    for (int n = 0; n < 16; ++n) Vt[n][o] = acc[n];
  }
  __syncthreads();  // Vt ready

  // ---- phase D: path math + u-reduction for both nodes (verbatim KD math) ----
#pragma unroll
  for (int it = 0; it < 2; ++it) {
    const int ln = ni + 8 * it;
    const float h0 = (it == 0) ? h0A : h0B;
    const float h1a = (it == 0) ? h1A[0] : h1B[0];
    const float h1b = (it == 0) ? h1A[1] : h1B[1];
    const float h1c = (it == 0) ? h1A[2] : h1B[2];
    float h2v[5];
#pragma unroll
    for (int j = 0; j < 5; ++j) h2v[j] = (it == 0) ? h2A[j] : h2B[j];

    const float* Vp = &Vt[ln][u];
    const float v0 = Vp[0], v15 = Vp[32], v2 = Vp[64], v3 = Vp[96];
    const float v5 = Vp[128], v6 = Vp[160];

    const float d11 = h1a * h1a + h1b * h1b + h1c * h1c;
    const float d22 = h2v[0] * h2v[0] + h2v[1] * h2v[1] + h2v[2] * h2v[2] +
                      h2v[3] * h2v[3] + h2v[4] * h2v[4];
    float y0 = v0 * h0 * h0 + v2 * d11 * ISQRT3 + v5 * d22 * ISQRT5;

    const float o00 = h1a * h1a, o01 = h1a * h1b, o02 = h1a * h1c;
    const float o11 = h1b * h1b, o12 = h1b * h1c, o22 = h1c * h1c;
    const float t40 = TWOS2f * o01, t41 = TWOS2f * o12;
    const float t42 = S6f * (2.f * o22 - o00 - o11);
    const float t43 = TWOS2f * o02, t44 = S2f * (o00 - o11);

    const float A00 = -S6f * h2v[2] + S2f * h2v[4];
    const float A01 = S2f * h2v[0];
    const float A02 = S2f * h2v[3];
    const float A11 = -S6f * h2v[2] - S2f * h2v[4];
    const float A12 = S2f * h2v[1];
    const float A22 = TWOS6f * h2v[2];
    const float B00 = A00 * A00 + A01 * A01 + A02 * A02;
    const float B01 = A00 * A01 + A01 * A11 + A02 * A12;
    const float B02 = A00 * A02 + A01 * A12 + A02 * A22;
    const float B11 = A01 * A01 + A11 * A11 + A12 * A12;
    const float B12 = A01 * A02 + A11 * A12 + A12 * A22;
    const float B22 = A02 * A02 + A12 * A12 + A22 * A22;
    const float t80 = TWOS2f * B01, t81 = TWOS2f * B12;
    const float t82 = S6f * (2.f * B22 - B00 - B11);
    const float t83 = TWOS2f * B02, t84 = S2f * (B00 - B11);

    const float w15 = v15 * h0;
    const float v6n = v6 * norm2;
    float y2r[5];
    y2r[0] = w15 * h2v[0] + v3 * t40 + v6n * t80;
    y2r[1] = w15 * h2v[1] + v3 * t41 + v6n * t81;
    y2r[2] = w15 * h2v[2] + v3 * t42 + v6n * t82;
    y2r[3] = w15 * h2v[3] + v3 * t43 + v6n * t83;
    y2r[4] = w15 * h2v[4] + v3 * t44 + v6n * t84;

#pragma unroll
    for (int off = 16; off > 0; off >>= 1) {
      y0 += __shfl_xor(y0, off, 32);
#pragma unroll
      for (int r = 0; r < 5; ++r) y2r[r] += __shfl_xor(y2r[r], off, 32);
    }

    if (u == 0) {
      sphs[ln][0] = y0;
#pragma unroll
      for (int r = 0; r < 5; ++r) sphs[ln][1 + r] = y2r[r];
    }
  }
  __syncthreads();

  // ---- phase E: Q-contract + segment atomics over the 16-node tile ----
  if (tid < 9) {
    const float QW[9][6] = {
        {ISQRT3, 0.f, 0.f, -S6f, 0.f, S2f},
        {0.f, S2f, 0.f, 0.f, 0.f, 0.f},
        {0.f, 0.f, 0.f, 0.f, S2f, 0.f},
        {0.f, S2f, 0.f, 0.f, 0.f, 0.f},
        {ISQRT3, 0.f, 0.f, -S6f, 0.f, -S2f},
        {0.f, 0.f, S2f, 0.f, 0.f, 0.f},
        {0.f, 0.f, 0.f, 0.f, S2f, 0.f},
        {0.f, 0.f, S2f, 0.f, 0.f, 0.f},
        {ISQRT3, 0.f, 0.f, TWOS6f, 0.f, 0.f}};
    const int a = tid / 3, b = tid % 3;
    const int rolled = ((a + 1) % 3) * 3 + ((b + 1) % 3);
    const float c0 = QW[tid][0], c1 = QW[tid][1], c2 = QW[tid][2];
    const float c3 = QW[tid][3], c4 = QW[tid][4], c5 = QW[tid][5];
    int cur_g = batch[n0];
    float acc = 0.f;
#pragma unroll
    for (int q = 0; q < 16; ++q) {
      const int g = batch[n0 + q];
      const float val = c0 * sphs[q][0] + c1 * sphs[q][1] + c2 * sphs[q][2] +
                        c3 * sphs[q][3] + c4 * sphs[q][4] + c5 * sphs[q][5];
      if (g != cur_g) {
        atomicAdd(out + cur_g * 9 + rolled, acc);
        acc = 0.f;
        cur_g = g;
      }
      acc += val;
    }
    atomicAdd(out + cur_g * 9 + rolled, acc);
  }
}

extern "C" void kernel_launch(void* const* d_in, const int* in_sizes, int n_in,
                              void* d_out, int out_size, void* d_ws, size_t ws_size,
                              hipStream_t stream) {
  const float* x_scalar = (const float*)d_in[0];
  const float* x_sph    = (const float*)d_in[1];
  const int*   batch    = (const int*)d_in[2];
  const float* W0e      = (const float*)d_in[3];
  const float* W1o      = (const float*)d_in[4];
  const float* W2e      = (const float*)d_in[5];
  const float* Wm1      = (const float*)d_in[6];
  const float* bm1      = (const float*)d_in[7];
  const float* Wm2      = (const float*)d_in[8];
  const float* bm2      = (const float*)d_in[9];
  const float* P0       = (const float*)d_in[10];
  // P1 (d_in[11]) provably unused: C111/C221 antisymmetric vs h(x)h of same h.
  const float* P2       = (const float*)d_in[12];
  float* ws  = (float*)d_ws;
  float* out = (float*)d_out;

  if (ws_size < (size_t)WS_FLOATS * sizeof(float)) return;

  // host-side C222 normalization (pure CPU double math; = sqrt(12/7))
  double Q2[5][3][3] = {};
  const double s2d = 0.70710678118654752440, s6d = 0.40824829046386301637;
  Q2[0][0][1] = Q2[0][1][0] = s2d;
  Q2[1][1][2] = Q2[1][2][1] = s2d;
  Q2[2][0][0] = Q2[2][1][1] = -s6d; Q2[2][2][2] = 2.0 * s6d;
  Q2[3][0][2] = Q2[3][2][0] = s2d;
  Q2[4][0][0] = s2d; Q2[4][1][1] = -s2d;
  double ss = 0.0;
  for (int i = 0; i < 5; ++i)
    for (int jj = 0; jj < 5; ++jj) {
      double S[3][3];
      for (int a = 0; a < 3; ++a)
        for (int d = 0; d < 3; ++d) {
          double m1 = 0, m2 = 0;
          for (int b = 0; b < 3; ++b) {
            m1 += Q2[i][a][b] * Q2[jj][d][b];
            m2 += Q2[i][d][b] * Q2[jj][a][b];
          }
          S[a][d] = 0.5 * (m1 + m2);
        }
      double tr = (S[0][0] + S[1][1] + S[2][2]) / 3.0;
      S[0][0] -= tr; S[1][1] -= tr; S[2][2] -= tr;
      for (int kk = 0; kk < 5; ++kk) {
        double cc = 0;
        for (int a = 0; a < 3; ++a)
          for (int d = 0; d < 3; ++d) cc += Q2[kk][a][d] * S[a][d];
        ss += cc * cc;
      }
    }
  const float norm2 = (float)sqrt(5.0 / ss);

  prep_kernel<<<49, 256, 0, stream>>>(Wm2, bm2, P0, P2, ws, out);
  fused_kernel<<<1250, 256, 0, stream>>>(x_scalar, x_sph, W0e, W1o, W2e,
                                         Wm1, bm1, ws, batch, out, norm2);
}